// Round 1
// baseline (1742.665 us; speedup 1.0000x reference)
//
#include <hip/hip_runtime.h>

// DRL4SSP pointer-network decoder, MI355X (gfx950).
// B=64 independent sequences -> 64 blocks x 512 threads; 127 sequential steps
// with 12 __syncthreads per step. All step-invariant matrices precomputed into
// d_ws; per-thread fragments register-cached; 128-vector broadcasts via
// 1 LDS read + v_readlane.

namespace {

constexpr int kB = 64, kSS = 8, kDS = 4, kH = 128, kS = 128, kT = 127, kG3 = 384;

// workspace layout (float offsets)
constexpr size_t OFF_BASE1 = 0;
constexpr size_t OFF_BASE2 = OFF_BASE1 + (size_t)kB * kH * kS;   // 1,048,576
constexpr size_t OFF_SHG   = OFF_BASE2 + (size_t)kB * kH * kS;
constexpr size_t OFF_DHG   = OFF_SHG   + (size_t)kB * kH * kS;
constexpr size_t OFF_SHT   = OFF_DHG   + (size_t)kB * kH * kS;
constexpr size_t OFF_WCOMB = OFF_SHT   + (size_t)kB * kS * kH;
constexpr size_t OFF_BCOMB = OFF_WCOMB + (size_t)kG3 * kSS;
constexpr size_t OFF_W1HT  = OFF_BCOMB + (size_t)kG3;
constexpr size_t OFF_W2DT  = OFF_W1HT  + (size_t)kH * kH;
// total = OFF_W2DT + kH*kH = 5,279,104 floats = ~21.1 MB

__device__ __forceinline__ float rlane(float v, int l) {
  return __uint_as_float(__builtin_amdgcn_readlane(__float_as_uint(v), (unsigned)l));
}

__device__ __forceinline__ float tanh_fast(float x) {
  // tanh(x) = (1 - e)/(1 + e), e = exp(-2x); valid for both signs, clamp for safety.
  x = fminf(15.f, fmaxf(-15.f, x));
  float e = __expf(-2.f * x);
  return (1.f - e) * __builtin_amdgcn_rcpf(1.f + e);
}

// ---------------- precompute kernels ----------------

// Wcomb = W_ih @ W_dec (384x8), bcomb = b_ih + W_ih@b_dec, w1hT/w2dT transposes.
__global__ void prep_w(const float* __restrict__ W_ih, const float* __restrict__ W_dec,
                       const float* __restrict__ b_ih, const float* __restrict__ b_dec,
                       const float* __restrict__ ww1, const float* __restrict__ ww2,
                       float* __restrict__ ws) {
  const int tid = threadIdx.x;
  float* Wcomb = ws + OFF_WCOMB;
  float* bcomb = ws + OFF_BCOMB;
  float* w1hT  = ws + OFF_W1HT;
  float* w2dT  = ws + OFF_W2DT;
  for (int idx = tid; idx < kG3 * kSS; idx += 256) {
    int j = idx >> 3, i = idx & 7;
    float acc = 0.f;
    for (int k = 0; k < kH; ++k) acc = fmaf(W_ih[j * kH + k], W_dec[k * kSS + i], acc);
    Wcomb[idx] = acc;
  }
  for (int j = tid; j < kG3; j += 256) {
    float acc = b_ih[j];
    for (int k = 0; k < kH; ++k) acc = fmaf(W_ih[j * kH + k], b_dec[k], acc);
    bcomb[j] = acc;
  }
  for (int idx = tid; idx < kH * kH; idx += 256) {
    int k = idx >> 7, h = idx & 127;
    w1hT[idx] = ww1[h * kG3 + 2 * kH + k];  // w1h = ww1[:, 2H:3H]
    w2dT[idx] = ww2[h * kG3 + kH + k];      // w2d = ww2[:, H:2H]
  }
}

// static_h / dynamic_h in [b][k][s] layout + static_h transposed [b][s][k].
__global__ void prep_sh(const float* __restrict__ stat_g, const float* __restrict__ dyn_g,
                        const float* __restrict__ W_s, const float* __restrict__ b_s,
                        const float* __restrict__ W_d, const float* __restrict__ b_d,
                        float* __restrict__ ws) {
  const int b = blockIdx.x, tid = threadIdx.x;
  float* sh_g = ws + OFF_SHG;
  float* dh_g = ws + OFF_DHG;
  float* shT  = ws + OFF_SHT;
  const float* sb = stat_g + (size_t)b * kSS * kS;
  const float* db = dyn_g + (size_t)b * kDS * kS;
  for (int idx = tid; idx < kH * kS; idx += 256) {
    int k = idx >> 7, s = idx & 127;
    float acc = b_s[k];
#pragma unroll
    for (int i = 0; i < kSS; ++i) acc = fmaf(W_s[k * kSS + i], sb[i * kS + s], acc);
    sh_g[(size_t)b * kH * kS + idx] = acc;
    float accd = b_d[k];
#pragma unroll
    for (int i = 0; i < kDS; ++i) accd = fmaf(W_d[k * kDS + i], db[i * kS + s], accd);
    dh_g[(size_t)b * kH * kS + idx] = accd;
  }
  for (int idx = tid; idx < kS * kH; idx += 256) {
    int s = idx >> 7, k = idx & 127;
    float acc = b_s[k];
#pragma unroll
    for (int i = 0; i < kSS; ++i) acc = fmaf(W_s[k * kSS + i], sb[i * kS + s], acc);
    shT[(size_t)b * kS * kH + idx] = acc;
  }
}

// base1 = ww1[:, :2H] @ [sh; dh]; base2 = ww2[:, :H]@sh + ww2[:, 2H:]@dh. Layout [b][h][s].
__global__ void prep_base(const float* __restrict__ ww1, const float* __restrict__ ww2,
                          float* __restrict__ ws) {
  const int b = blockIdx.x, which = blockIdx.y, tid = threadIdx.x;
  const float* sh_g = ws + OFF_SHG + (size_t)b * kH * kS;
  const float* dh_g = ws + OFF_DHG + (size_t)b * kH * kS;
  const float* ww = which ? ww2 : ww1;
  const int dh_off = which ? 2 * kH : kH;
  float* dst = ws + (which ? OFF_BASE2 : OFF_BASE1) + (size_t)b * kH * kS;
  for (int idx = tid; idx < kH * kS / 4; idx += 256) {
    int h = idx >> 5, sq = idx & 31;  // 4 consecutive s per thread
    const float* wrow = ww + h * kG3;
    float4 acc = make_float4(0.f, 0.f, 0.f, 0.f);
#pragma unroll 8
    for (int k = 0; k < kH; ++k) {
      float w = wrow[k];
      float4 v = *reinterpret_cast<const float4*>(sh_g + k * kS + sq * 4);
      acc.x = fmaf(w, v.x, acc.x); acc.y = fmaf(w, v.y, acc.y);
      acc.z = fmaf(w, v.z, acc.z); acc.w = fmaf(w, v.w, acc.w);
    }
#pragma unroll 8
    for (int k = 0; k < kH; ++k) {
      float w = wrow[dh_off + k];
      float4 v = *reinterpret_cast<const float4*>(dh_g + k * kS + sq * 4);
      acc.x = fmaf(w, v.x, acc.x); acc.y = fmaf(w, v.y, acc.y);
      acc.z = fmaf(w, v.z, acc.z); acc.w = fmaf(w, v.w, acc.w);
    }
    *reinterpret_cast<float4*>(dst + h * kS + sq * 4) = acc;
  }
}

// ---------------- main sequential kernel ----------------

__global__ __launch_bounds__(512, 2) void ptrnet_main(
    const float* __restrict__ stat_g, const float* __restrict__ dyn_g,
    const float* __restrict__ vv1_g, const float* __restrict__ vv2_g,
    const float* __restrict__ bhh_g, const float* __restrict__ Whh_g,
    const float* __restrict__ ws, float* __restrict__ out) {
  const int b = blockIdx.x;
  const int tid = threadIdx.x;
  const int hh = tid & 127;        // output index within 128 (also "s" in attn phases)
  const int seg = tid >> 7;        // 0..3, each seg covers a 32-chunk of k/h-rows
  const int lane = tid & 63;
  const int wave = tid >> 6;

  __shared__ float h_lds[kH], hn_lds[kH];
  __shared__ float gi_l[kG3], gh_l[kG3];
  __shared__ float e1[kS];
  __shared__ float pu[4][kS], pa[4][kS];
  __shared__ float mask[kS];
  __shared__ float dec_l[kSS];
  __shared__ float stat_l[kSS * kS];
  __shared__ float wredf[4];
  __shared__ int iredi[2];
  __shared__ int ptr_sh;
  __shared__ float rinv_sh;

  const float* base1 = ws + OFF_BASE1 + (size_t)b * kH * kS;
  const float* base2 = ws + OFF_BASE2 + (size_t)b * kH * kS;
  const float* shT   = ws + OFF_SHT   + (size_t)b * kS * kH;
  const float* Wcomb = ws + OFF_WCOMB;
  const float* bcomb = ws + OFF_BCOMB;
  const float* w1hT  = ws + OFF_W1HT;
  const float* w2dT  = ws + OFF_W2DT;

  // ---- persistent register caches ----
  float wcr[8]; float bc_r = 0.f, bh_r = 0.f;
  if (tid < kG3) {
#pragma unroll
    for (int i = 0; i < 8; ++i) wcr[i] = Wcomb[tid * 8 + i];
    bc_r = bcomb[tid];
    bh_r = bhh_g[tid];
  }
  float w1r[32], w2r[32], b1r[32], b2r[32], shr[32];
#pragma unroll
  for (int kk = 0; kk < 32; ++kk) {
    int row = seg * 32 + kk;
    w1r[kk] = w1hT[row * kH + hh];
    w2r[kk] = w2dT[row * kH + hh];
    b1r[kk] = base1[row * kS + hh];   // base1[hrow][s=hh]
    b2r[kk] = base2[row * kS + hh];
    shr[kk] = shT[row * kH + hh];     // static_h[s=row][h=hh]
  }
  float v_vv1 = vv1_g[seg * 32 + (lane & 31)];
  float v_vv2 = vv2_g[seg * 32 + (lane & 31)];

  // ---- LDS init ----
  for (int i = tid; i < kH; i += 512) h_lds[i] = 0.f;
  for (int i = tid; i < kSS * kS; i += 512) stat_l[i] = stat_g[(size_t)b * kSS * kS + i];
  if (tid < kSS) dec_l[tid] = 0.f;
  for (int i = tid; i < kS; i += 512)
    mask[i] = (i == 0 || dyn_g[(size_t)b * kDS * kS + i] != 0.f) ? 0.f : 1.f;
  __syncthreads();

  float attn1_reg = 0.f, logit_reg = 0.f;

  for (int t = 0; t < kT; ++t) {
    // ---- P0: gi = Wcomb@dec_in + bcomb; gh = Whh@h + bhh ----
    if (tid < kG3) {
      float v_dec = dec_l[lane & 7];
      float gi = bc_r;
#pragma unroll
      for (int i = 0; i < 8; ++i) gi = fmaf(rlane(v_dec, i), wcr[i], gi);
      gi_l[tid] = gi;

      float v_h0 = h_lds[lane];
      float v_h1 = h_lds[64 + lane];
      const float* wrow = Whh_g + tid * kH;
      float acc = bh_r;
#pragma unroll
      for (int c = 0; c < 16; ++c) {
        float4 w4 = *reinterpret_cast<const float4*>(wrow + c * 4);
        acc = fmaf(rlane(v_h0, 4 * c + 0), w4.x, acc);
        acc = fmaf(rlane(v_h0, 4 * c + 1), w4.y, acc);
        acc = fmaf(rlane(v_h0, 4 * c + 2), w4.z, acc);
        acc = fmaf(rlane(v_h0, 4 * c + 3), w4.w, acc);
      }
#pragma unroll
      for (int c = 16; c < 32; ++c) {
        float4 w4 = *reinterpret_cast<const float4*>(wrow + c * 4);
        acc = fmaf(rlane(v_h1, 4 * c - 64), w4.x, acc);
        acc = fmaf(rlane(v_h1, 4 * c - 63), w4.y, acc);
        acc = fmaf(rlane(v_h1, 4 * c - 62), w4.z, acc);
        acc = fmaf(rlane(v_h1, 4 * c - 61), w4.w, acc);
      }
      gh_l[tid] = acc;
    }
    __syncthreads();

    // ---- P1: GRU cell -> h_new ----
    if (tid < kH) {
      float ir = gi_l[tid], iz = gi_l[tid + kH], inn = gi_l[tid + 2 * kH];
      float hr = gh_l[tid], hz = gh_l[tid + kH], hn_g = gh_l[tid + 2 * kH];
      float r = 1.f / (1.f + __expf(-(ir + hr)));
      float z = 1.f / (1.f + __expf(-(iz + hz)));
      float x = inn + r * hn_g;
      x = fminf(15.f, fmaxf(-15.f, x));
      float e = __expf(-2.f * x);
      float n = (1.f - e) / (1.f + e);
      hn_lds[tid] = (1.f - z) * n + z * h_lds[tid];
    }
    __syncthreads();

    // ---- P2: u1 partials  (u1[hh] = sum_k h_new[k]*w1h[hh][k]) ----
    {
      float v_hn = hn_lds[seg * 32 + (lane & 31)];
      float acc = 0.f;
#pragma unroll
      for (int kk = 0; kk < 32; ++kk) acc = fmaf(rlane(v_hn, kk), w1r[kk], acc);
      pu[seg][hh] = acc;
    }
    __syncthreads();

    // ---- P3: attn1 partials (s = hh), u1 assembled per-lane ----
    {
      int li = seg * 32 + (lane & 31);
      float v_u1 = (pu[0][li] + pu[1][li]) + (pu[2][li] + pu[3][li]);
      float acc = 0.f;
#pragma unroll
      for (int kk = 0; kk < 32; ++kk) {
        float x = b1r[kk] + rlane(v_u1, kk);
        acc = fmaf(rlane(v_vv1, kk), tanh_fast(x), acc);
      }
      pa[seg][hh] = acc;
    }
    __syncthreads();

    // ---- P3b: attn1 reduce + wave max ----
    if (tid < kS) {
      float a = (pa[0][tid] + pa[1][tid]) + (pa[2][tid] + pa[3][tid]);
      attn1_reg = a;
      float m = a;
#pragma unroll
      for (int off = 32; off >= 1; off >>= 1) m = fmaxf(m, __shfl_xor(m, off));
      if (lane == 0) wredf[wave] = m;
    }
    __syncthreads();

    // ---- P3c: softmax1 exp + wave sum ----
    if (tid < kS) {
      float m = fmaxf(wredf[0], wredf[1]);
      float e = __expf(attn1_reg - m);
      e1[tid] = e;
      float sum = e;
#pragma unroll
      for (int off = 32; off >= 1; off >>= 1) sum += __shfl_xor(sum, off);
      if (lane == 0) wredf[2 + wave] = sum;
    }
    __syncthreads();

    // ---- P4: dytext partials (over s chunks); tid0 computes 1/sum ----
    {
      if (tid == 0) rinv_sh = 1.f / (wredf[2] + wredf[3]);
      float v_e = e1[seg * 32 + (lane & 31)];
      float acc = 0.f;
#pragma unroll
      for (int kk = 0; kk < 32; ++kk) acc = fmaf(rlane(v_e, kk), shr[kk], acc);
      pu[seg][hh] = acc;
    }
    __syncthreads();

    // ---- P5: u2 partials (u2raw[hh] = sum_k dyraw[k]*w2d[hh][k]) ----
    {
      int li = seg * 32 + (lane & 31);
      float v_dy = (pu[0][li] + pu[1][li]) + (pu[2][li] + pu[3][li]);
      float acc = 0.f;
#pragma unroll
      for (int kk = 0; kk < 32; ++kk) acc = fmaf(rlane(v_dy, kk), w2r[kk], acc);
      pa[seg][hh] = acc;
    }
    __syncthreads();

    // ---- P6: attn2 partials (s = hh); u2 = rinv * u2raw ----
    {
      float rin = rinv_sh;
      int li = seg * 32 + (lane & 31);
      float v_u2 = ((pa[0][li] + pa[1][li]) + (pa[2][li] + pa[3][li])) * rin;
      float acc = 0.f;
#pragma unroll
      for (int kk = 0; kk < 32; ++kk) {
        float x = b2r[kk] + rlane(v_u2, kk);
        acc = fmaf(rlane(v_vv2, kk), tanh_fast(x), acc);
      }
      pu[seg][hh] = acc;
    }
    __syncthreads();

    // ---- P6b: logits + wave argmax (first-max tie-break) ----
    if (tid < kS) {
      float a2 = (pu[0][tid] + pu[1][tid]) + (pu[2][tid] + pu[3][tid]);
      logit_reg = a2 + (mask[tid] > 0.f ? 0.f : -1e30f);
      float mv = logit_reg; int mi = tid;
#pragma unroll
      for (int off = 32; off >= 1; off >>= 1) {
        float ov = __shfl_xor(mv, off);
        int oi = __shfl_xor(mi, off);
        if (ov > mv || (ov == mv && oi < mi)) { mv = ov; mi = oi; }
      }
      if (lane == 0) { wredf[wave] = mv; iredi[wave] = mi; }
    }
    __syncthreads();

    // ---- P7: combine argmax, exp-sum for log_softmax ----
    if (tid < kS) {
      float mv0 = wredf[0], mv1 = wredf[1];
      float m; int ptr;
      if (mv0 > mv1 || (mv0 == mv1 && iredi[0] < iredi[1])) { m = mv0; ptr = iredi[0]; }
      else { m = mv1; ptr = iredi[1]; }
      if (tid == 0) ptr_sh = ptr;
      float e = __expf(logit_reg - m);
      float sum = e;
#pragma unroll
      for (int off = 32; off >= 1; off >>= 1) sum += __shfl_xor(sum, off);
      if (lane == 0) wredf[2 + wave] = sum;
    }
    __syncthreads();

    // ---- P8: outputs + state updates ----
    if (tid == 0) {
      float se = wredf[2] + wredf[3];
      float logp = -__logf(se);   // logits[ptr] == max exactly
      out[b * kT + t] = (float)ptr_sh;
      out[kB * kT + b * kT + t] = logp;
      mask[ptr_sh] = 0.f;
    }
    if (tid < kSS) dec_l[tid] = stat_l[tid * kS + ptr_sh];
    if (tid >= 128 && tid < 256) h_lds[tid - 128] = hn_lds[tid - 128];
    __syncthreads();
  }
}

}  // namespace

extern "C" void kernel_launch(void* const* d_in, const int* in_sizes, int n_in,
                              void* d_out, int out_size, void* d_ws, size_t ws_size,
                              hipStream_t stream) {
  const float* stat_g = (const float*)d_in[0];
  const float* dyn_g  = (const float*)d_in[1];
  // d_in[2] transition_time: unused by the reference computation
  const float* W_s   = (const float*)d_in[3];
  const float* b_s   = (const float*)d_in[4];
  const float* W_d   = (const float*)d_in[5];
  const float* b_d   = (const float*)d_in[6];
  // W_dec/b_dec folded into Wcomb/bcomb
  const float* W_dec = (const float*)d_in[7];
  const float* b_dec = (const float*)d_in[8];
  const float* vv1   = (const float*)d_in[9];
  const float* ww1   = (const float*)d_in[10];
  const float* vv2   = (const float*)d_in[11];
  const float* ww2   = (const float*)d_in[12];
  const float* W_ih  = (const float*)d_in[13];
  const float* W_hh  = (const float*)d_in[14];
  const float* b_ih  = (const float*)d_in[15];
  const float* b_hh  = (const float*)d_in[16];

  float* ws = (float*)d_ws;
  float* out = (float*)d_out;

  prep_w<<<1, 256, 0, stream>>>(W_ih, W_dec, b_ih, b_dec, ww1, ww2, ws);
  prep_sh<<<kB, 256, 0, stream>>>(stat_g, dyn_g, W_s, b_s, W_d, b_d, ws);
  prep_base<<<dim3(kB, 2), 256, 0, stream>>>(ww1, ww2, ws);
  ptrnet_main<<<kB, 512, 0, stream>>>(stat_g, dyn_g, vv1, vv2, b_hh, W_hh, ws, out);
}

// Round 2
// 1615.462 us; speedup vs baseline: 1.0787x; 1.0787x over previous
//
#include <hip/hip_runtime.h>

// DRL4SSP pointer-network decoder, MI355X (gfx950).
// 64 batches -> 64 blocks x 512 threads, 127 sequential steps, 7 barriers/step.
// All step-invariant matrices in LDS (161 KB dynamic) or registers; zero global
// loads inside the step loop. 128-vector broadcasts via 1 LDS read + v_readlane.

namespace {

constexpr int kB = 64, kSS = 8, kDS = 4, kH = 128, kS = 128, kT = 127, kG3 = 384;

// workspace layout (float offsets)
constexpr size_t OFF_BASE1 = 0;
constexpr size_t OFF_BASE2 = OFF_BASE1 + (size_t)kB * kH * kS;
constexpr size_t OFF_SHG   = OFF_BASE2 + (size_t)kB * kH * kS;
constexpr size_t OFF_DHG   = OFF_SHG   + (size_t)kB * kH * kS;
constexpr size_t OFF_SHT   = OFF_DHG   + (size_t)kB * kH * kS;
constexpr size_t OFF_WCT   = OFF_SHT   + (size_t)kB * kS * kH;  // WcombT [8][384]
constexpr size_t OFF_BCOMB = OFF_WCT   + (size_t)kSS * kG3;
constexpr size_t OFF_W1HT  = OFF_BCOMB + (size_t)kG3;
constexpr size_t OFF_W2DT  = OFF_W1HT  + (size_t)kH * kH;
// total = OFF_W2DT + kH*kH = 5,279,104 floats (~21.1 MB)

// dynamic-LDS layout (float offsets)
constexpr int L_BASE1 = 0;        // 16384
constexpr int L_BASE2 = 16384;    // 16384
constexpr int L_WCT   = 32768;    // 3072
constexpr int L_BC    = 35840;    // 384
constexpr int L_BH    = 36224;    // 384
constexpr int L_STAT  = 36608;    // 1024
constexpr int L_PG    = 37632;    // 1536  [seg][gate][128]
constexpr int L_PU    = 39168;    // 512
constexpr int L_PA    = 39680;    // 512
constexpr int L_MASK  = 40192;    // 128
constexpr int L_DEC   = 40320;    // 8
constexpr int L_WSUM  = 40328;    // 4
constexpr int L_RINV  = 40332;    // 1
constexpr int LDS_FLOATS = 40336;
constexpr int LDS_BYTES  = LDS_FLOATS * 4;  // 161,344 <= 163,840

__device__ __forceinline__ float rlane(float v, int l) {
  return __uint_as_float(__builtin_amdgcn_readlane(__float_as_uint(v), (unsigned)l));
}

__device__ __forceinline__ float tanh_fast(float x) {
  // identical to the round-1 (passing) formula — trajectory-sensitive
  x = fminf(15.f, fmaxf(-15.f, x));
  float e = __expf(-2.f * x);
  return (1.f - e) * __builtin_amdgcn_rcpf(1.f + e);
}

// ---------------- precompute kernels ----------------

__global__ void prep_w(const float* __restrict__ W_ih, const float* __restrict__ W_dec,
                       const float* __restrict__ b_ih, const float* __restrict__ b_dec,
                       const float* __restrict__ ww1, const float* __restrict__ ww2,
                       float* __restrict__ ws) {
  const int tid = threadIdx.x;
  float* WcT  = ws + OFF_WCT;    // [i][j] = sum_k W_ih[j,k] W_dec[k,i]
  float* bcomb = ws + OFF_BCOMB;
  float* w1hT  = ws + OFF_W1HT;
  float* w2dT  = ws + OFF_W2DT;
  for (int idx = tid; idx < kSS * kG3; idx += 256) {
    int i = idx / kG3, j = idx % kG3;
    float acc = 0.f;
    for (int k = 0; k < kH; ++k) acc = fmaf(W_ih[j * kH + k], W_dec[k * kSS + i], acc);
    WcT[idx] = acc;
  }
  for (int j = tid; j < kG3; j += 256) {
    float acc = b_ih[j];
    for (int k = 0; k < kH; ++k) acc = fmaf(W_ih[j * kH + k], b_dec[k], acc);
    bcomb[j] = acc;
  }
  for (int idx = tid; idx < kH * kH; idx += 256) {
    int k = idx >> 7, h = idx & 127;
    w1hT[idx] = ww1[h * kG3 + 2 * kH + k];  // w1h = ww1[:, 2H:3H]
    w2dT[idx] = ww2[h * kG3 + kH + k];      // w2d = ww2[:, H:2H]
  }
}

__global__ void prep_sh(const float* __restrict__ stat_g, const float* __restrict__ dyn_g,
                        const float* __restrict__ W_s, const float* __restrict__ b_s,
                        const float* __restrict__ W_d, const float* __restrict__ b_d,
                        float* __restrict__ ws) {
  const int b = blockIdx.x, tid = threadIdx.x;
  float* sh_g = ws + OFF_SHG;
  float* dh_g = ws + OFF_DHG;
  float* shT  = ws + OFF_SHT;
  const float* sb = stat_g + (size_t)b * kSS * kS;
  const float* db = dyn_g + (size_t)b * kDS * kS;
  for (int idx = tid; idx < kH * kS; idx += 256) {
    int k = idx >> 7, s = idx & 127;
    float acc = b_s[k];
#pragma unroll
    for (int i = 0; i < kSS; ++i) acc = fmaf(W_s[k * kSS + i], sb[i * kS + s], acc);
    sh_g[(size_t)b * kH * kS + idx] = acc;
    float accd = b_d[k];
#pragma unroll
    for (int i = 0; i < kDS; ++i) accd = fmaf(W_d[k * kDS + i], db[i * kS + s], accd);
    dh_g[(size_t)b * kH * kS + idx] = accd;
  }
  for (int idx = tid; idx < kS * kH; idx += 256) {
    int s = idx >> 7, k = idx & 127;
    float acc = b_s[k];
#pragma unroll
    for (int i = 0; i < kSS; ++i) acc = fmaf(W_s[k * kSS + i], sb[i * kS + s], acc);
    shT[(size_t)b * kS * kH + idx] = acc;
  }
}

__global__ void prep_base(const float* __restrict__ ww1, const float* __restrict__ ww2,
                          float* __restrict__ ws) {
  const int b = blockIdx.x, which = blockIdx.y, tid = threadIdx.x;
  const float* sh_g = ws + OFF_SHG + (size_t)b * kH * kS;
  const float* dh_g = ws + OFF_DHG + (size_t)b * kH * kS;
  const float* ww = which ? ww2 : ww1;
  const int dh_off = which ? 2 * kH : kH;
  float* dst = ws + (which ? OFF_BASE2 : OFF_BASE1) + (size_t)b * kH * kS;
  for (int idx = tid; idx < kH * kS / 4; idx += 256) {
    int h = idx >> 5, sq = idx & 31;
    const float* wrow = ww + h * kG3;
    float4 acc = make_float4(0.f, 0.f, 0.f, 0.f);
#pragma unroll 8
    for (int k = 0; k < kH; ++k) {
      float w = wrow[k];
      float4 v = *reinterpret_cast<const float4*>(sh_g + k * kS + sq * 4);
      acc.x = fmaf(w, v.x, acc.x); acc.y = fmaf(w, v.y, acc.y);
      acc.z = fmaf(w, v.z, acc.z); acc.w = fmaf(w, v.w, acc.w);
    }
#pragma unroll 8
    for (int k = 0; k < kH; ++k) {
      float w = wrow[dh_off + k];
      float4 v = *reinterpret_cast<const float4*>(dh_g + k * kS + sq * 4);
      acc.x = fmaf(w, v.x, acc.x); acc.y = fmaf(w, v.y, acc.y);
      acc.z = fmaf(w, v.z, acc.z); acc.w = fmaf(w, v.w, acc.w);
    }
    *reinterpret_cast<float4*>(dst + h * kS + sq * 4) = acc;
  }
}

// ---------------- main sequential kernel ----------------

__global__ __launch_bounds__(512, 2) void ptrnet_main(
    const float* __restrict__ stat_g, const float* __restrict__ dyn_g,
    const float* __restrict__ vv1_g, const float* __restrict__ vv2_g,
    const float* __restrict__ bhh_g, const float* __restrict__ Whh_g,
    const float* __restrict__ ws, float* __restrict__ out) {
  extern __shared__ float sm[];
  const int b = blockIdx.x;
  const int tid = threadIdx.x;
  const int hh = tid & 127;          // output/s index
  const int seg = tid >> 7;          // 0..3: 32-wide k/h chunk
  const int lane = tid & 63;
  const int li = seg * 32 + (hh & 31);  // this thread's "owned" 128-index

  float* base1_l = sm + L_BASE1;
  float* base2_l = sm + L_BASE2;
  float* wct_l   = sm + L_WCT;
  float* bc_l    = sm + L_BC;
  float* bh_l    = sm + L_BH;
  float* stat_l  = sm + L_STAT;
  float* pg_l    = sm + L_PG;
  float* pu_l    = sm + L_PU;
  float* pa_l    = sm + L_PA;
  float* mask_l  = sm + L_MASK;
  float* dec_l   = sm + L_DEC;
  float* wsum_l  = sm + L_WSUM;
  float* rinv_l  = sm + L_RINV;

  // ---- LDS init (one-time) ----
  {
    const float4* b1g = reinterpret_cast<const float4*>(ws + OFF_BASE1 + (size_t)b * kH * kS);
    const float4* b2g = reinterpret_cast<const float4*>(ws + OFF_BASE2 + (size_t)b * kH * kS);
    float4* b1l = reinterpret_cast<float4*>(base1_l);
    float4* b2l = reinterpret_cast<float4*>(base2_l);
    for (int i = tid; i < kH * kS / 4; i += 512) { b1l[i] = b1g[i]; b2l[i] = b2g[i]; }
    for (int i = tid; i < kSS * kG3; i += 512) wct_l[i] = ws[OFF_WCT + i];
    if (tid < kG3) { bc_l[tid] = ws[OFF_BCOMB + tid]; bh_l[tid] = bhh_g[tid]; }
    for (int i = tid; i < kSS * kS; i += 512) stat_l[i] = stat_g[(size_t)b * kSS * kS + i];
    if (tid < kS)
      mask_l[tid] = (tid == 0 || dyn_g[(size_t)b * kDS * kS + tid] != 0.f) ? 0.f : 1.f;
    if (tid < kSS) dec_l[tid] = 0.f;
  }

  // ---- persistent register caches ----
  float w1r[32], w2r[32], shr[32];
  {
    const float* w1hT = ws + OFF_W1HT;
    const float* w2dT = ws + OFF_W2DT;
    const float* shT  = ws + OFF_SHT + (size_t)b * kS * kH;
#pragma unroll
    for (int kk = 0; kk < 32; ++kk) {
      int row = seg * 32 + kk;
      w1r[kk] = w1hT[row * kH + hh];
      w2r[kk] = w2dT[row * kH + hh];
      shr[kk] = shT[row * kH + hh];
      asm volatile("" : "+v"(w1r[kk]), "+v"(w2r[kk]), "+v"(shr[kk]));
    }
  }
  float whr0[32], whr1[32], whr2[32];
#pragma unroll
  for (int q = 0; q < 8; ++q) {
    float4 a0 = *reinterpret_cast<const float4*>(Whh_g + (0 * kH + hh) * kH + seg * 32 + q * 4);
    float4 a1 = *reinterpret_cast<const float4*>(Whh_g + (1 * kH + hh) * kH + seg * 32 + q * 4);
    float4 a2 = *reinterpret_cast<const float4*>(Whh_g + (2 * kH + hh) * kH + seg * 32 + q * 4);
    whr0[q*4+0]=a0.x; whr0[q*4+1]=a0.y; whr0[q*4+2]=a0.z; whr0[q*4+3]=a0.w;
    whr1[q*4+0]=a1.x; whr1[q*4+1]=a1.y; whr1[q*4+2]=a1.z; whr1[q*4+3]=a1.w;
    whr2[q*4+0]=a2.x; whr2[q*4+1]=a2.y; whr2[q*4+2]=a2.z; whr2[q*4+3]=a2.w;
#pragma unroll
    for (int r = 0; r < 4; ++r)
      asm volatile("" : "+v"(whr0[q*4+r]), "+v"(whr1[q*4+r]), "+v"(whr2[q*4+r]));
  }
  float v_vv1 = vv1_g[li], v_vv2 = vv2_g[li];
  float h_prev = 0.f;
  __syncthreads();

  for (int t = 0; t < kT; ++t) {
    // ---- PH_A: gi (own li, kept in regs) + gh partials ----
    float gi0, gi1, gi2;
    {
      float v_dec = dec_l[lane & 7];
      gi0 = bc_l[li]; gi1 = bc_l[kH + li]; gi2 = bc_l[2 * kH + li];
#pragma unroll
      for (int i = 0; i < 8; ++i) {
        float d = rlane(v_dec, i);
        gi0 = fmaf(wct_l[i * kG3 + li], d, gi0);
        gi1 = fmaf(wct_l[i * kG3 + kH + li], d, gi1);
        gi2 = fmaf(wct_l[i * kG3 + 2 * kH + li], d, gi2);
      }
      float a0 = 0.f, a1 = 0.f, a2 = 0.f;
#pragma unroll
      for (int kk = 0; kk < 32; ++kk) {
        float hv = rlane(h_prev, kk);
        a0 = fmaf(whr0[kk], hv, a0);
        a1 = fmaf(whr1[kk], hv, a1);
        a2 = fmaf(whr2[kk], hv, a2);
      }
      pg_l[(seg * 3 + 0) * kS + hh] = a0;
      pg_l[(seg * 3 + 1) * kS + hh] = a1;
      pg_l[(seg * 3 + 2) * kS + hh] = a2;
    }
    __syncthreads();

    // ---- PH_B: GRU (replicated per-thread for own li) + u1 partials ----
    {
      float gh0 = bh_l[li] +
          ((pg_l[(0*3+0)*kS+li] + pg_l[(1*3+0)*kS+li]) + (pg_l[(2*3+0)*kS+li] + pg_l[(3*3+0)*kS+li]));
      float gh1 = bh_l[kH + li] +
          ((pg_l[(0*3+1)*kS+li] + pg_l[(1*3+1)*kS+li]) + (pg_l[(2*3+1)*kS+li] + pg_l[(3*3+1)*kS+li]));
      float gh2 = bh_l[2*kH + li] +
          ((pg_l[(0*3+2)*kS+li] + pg_l[(1*3+2)*kS+li]) + (pg_l[(2*3+2)*kS+li] + pg_l[(3*3+2)*kS+li]));
      float r = 1.f / (1.f + __expf(-(gi0 + gh0)));
      float z = 1.f / (1.f + __expf(-(gi1 + gh1)));
      float x = gi2 + r * gh2;
      x = fminf(15.f, fmaxf(-15.f, x));
      float e = __expf(-2.f * x);
      float n = (1.f - e) / (1.f + e);
      float hnew = (1.f - z) * n + z * h_prev;
      h_prev = hnew;
      float acc = 0.f;
#pragma unroll
      for (int kk = 0; kk < 32; ++kk) acc = fmaf(rlane(hnew, kk), w1r[kk], acc);
      pu_l[seg * kS + hh] = acc;
    }
    __syncthreads();

    // ---- PH_C: attn1 partials (tanh over 32 h-rows) ----
    {
      float v_u1 = (pu_l[li] + pu_l[kS + li]) + (pu_l[2*kS + li] + pu_l[3*kS + li]);
      float acc = 0.f;
#pragma unroll
      for (int kk = 0; kk < 32; ++kk) {
        float xx = base1_l[(seg * 32 + kk) * kS + hh] + rlane(v_u1, kk);
        acc = fmaf(rlane(v_vv1, kk), tanh_fast(xx), acc);
      }
      pa_l[seg * kS + hh] = acc;
    }
    __syncthreads();

    // ---- PH_E: softmax1 exp (no max-sub) + chunk sums + dytext partials ----
    {
      float a = (pa_l[li] + pa_l[kS + li]) + (pa_l[2*kS + li] + pa_l[3*kS + li]);
      float ee = __expf(fminf(a, 60.f));
      float ssum = ee;
#pragma unroll
      for (int off = 1; off < 32; off <<= 1) ssum += __shfl_xor(ssum, off);
      if ((lane & 31) == 0) wsum_l[seg] = ssum;
      float acc = 0.f;
#pragma unroll
      for (int kk = 0; kk < 32; ++kk) acc = fmaf(rlane(ee, kk), shr[kk], acc);
      pu_l[seg * kS + hh] = acc;
    }
    __syncthreads();

    // ---- PH_F: u2 partials; one thread computes 1/sum ----
    {
      float v_dy = (pu_l[li] + pu_l[kS + li]) + (pu_l[2*kS + li] + pu_l[3*kS + li]);
      float acc = 0.f;
#pragma unroll
      for (int kk = 0; kk < 32; ++kk) acc = fmaf(rlane(v_dy, kk), w2r[kk], acc);
      pa_l[seg * kS + hh] = acc;
      if (tid == 0) rinv_l[0] = 1.0f / ((wsum_l[0] + wsum_l[1]) + (wsum_l[2] + wsum_l[3]));
    }
    __syncthreads();

    // ---- PH_G: attn2 partials (tanh over 32 h-rows) ----
    {
      float rin = rinv_l[0];
      float v_u2 = ((pa_l[li] + pa_l[kS + li]) + (pa_l[2*kS + li] + pa_l[3*kS + li])) * rin;
      float acc = 0.f;
#pragma unroll
      for (int kk = 0; kk < 32; ++kk) {
        float xx = base2_l[(seg * 32 + kk) * kS + hh] + rlane(v_u2, kk);
        acc = fmaf(rlane(v_vv2, kk), tanh_fast(xx), acc);
      }
      pu_l[seg * kS + hh] = acc;
    }
    __syncthreads();

    // ---- PH_H: logits, argmax, logsumexp, state update (wave 0 only) ----
    if (tid < 64) {
      int s0 = lane, s1 = lane + 64;
      float l0 = (pu_l[s0] + pu_l[kS + s0]) + (pu_l[2*kS + s0] + pu_l[3*kS + s0]);
      float l1 = (pu_l[s1] + pu_l[kS + s1]) + (pu_l[2*kS + s1] + pu_l[3*kS + s1]);
      l0 += (mask_l[s0] > 0.f ? 0.f : -1e30f);
      l1 += (mask_l[s1] > 0.f ? 0.f : -1e30f);
      float es = __expf(l0) + __expf(l1);
      float mv; int mi;
      if (l1 > l0) { mv = l1; mi = s1; } else { mv = l0; mi = s0; }
#pragma unroll
      for (int off = 1; off < 64; off <<= 1) {
        float ov = __shfl_xor(mv, off);
        int oi = __shfl_xor(mi, off);
        if (ov > mv || (ov == mv && oi < mi)) { mv = ov; mi = oi; }
        es += __shfl_xor(es, off);
      }
      if (lane == 0) {
        out[b * kT + t] = (float)mi;
        out[kB * kT + b * kT + t] = mv - __logf(es);
        mask_l[mi] = 0.f;
      }
      if (lane < kSS) dec_l[lane] = stat_l[lane * kS + mi];
    }
    __syncthreads();
  }
}

}  // namespace

extern "C" void kernel_launch(void* const* d_in, const int* in_sizes, int n_in,
                              void* d_out, int out_size, void* d_ws, size_t ws_size,
                              hipStream_t stream) {
  const float* stat_g = (const float*)d_in[0];
  const float* dyn_g  = (const float*)d_in[1];
  const float* W_s   = (const float*)d_in[3];
  const float* b_s   = (const float*)d_in[4];
  const float* W_d   = (const float*)d_in[5];
  const float* b_d   = (const float*)d_in[6];
  const float* W_dec = (const float*)d_in[7];
  const float* b_dec = (const float*)d_in[8];
  const float* vv1   = (const float*)d_in[9];
  const float* ww1   = (const float*)d_in[10];
  const float* vv2   = (const float*)d_in[11];
  const float* ww2   = (const float*)d_in[12];
  const float* W_ih  = (const float*)d_in[13];
  const float* W_hh  = (const float*)d_in[14];
  const float* b_ih  = (const float*)d_in[15];
  const float* b_hh  = (const float*)d_in[16];

  float* ws = (float*)d_ws;
  float* out = (float*)d_out;

  static bool attr_set = false;
  (void)attr_set;
  hipFuncSetAttribute(reinterpret_cast<const void*>(ptrnet_main),
                      hipFuncAttributeMaxDynamicSharedMemorySize, LDS_BYTES);

  prep_w<<<1, 256, 0, stream>>>(W_ih, W_dec, b_ih, b_dec, ww1, ww2, ws);
  prep_sh<<<kB, 256, 0, stream>>>(stat_g, dyn_g, W_s, b_s, W_d, b_d, ws);
  prep_base<<<dim3(kB, 2), 256, 0, stream>>>(ww1, ww2, ws);
  ptrnet_main<<<kB, 512, LDS_BYTES, stream>>>(stat_g, dyn_g, vv1, vv2, b_hh, W_hh, ws, out);
}